// Round 8
// baseline (316.212 us; speedup 1.0000x reference)
//
#include <hip/hip_runtime.h>

typedef unsigned short u16;
typedef __attribute__((ext_vector_type(8))) short short8;
typedef __attribute__((ext_vector_type(4))) float f32x4;

#define DEV static __device__ __forceinline__

DEV float bf2f(u16 u) { return __uint_as_float(((unsigned)u) << 16); }
DEV u16 f2bf(float f) {
  unsigned u = __float_as_uint(f);
  return (u16)((u + 0x7fffu + ((u >> 16) & 1u)) >> 16);
}

// async global->LDS, 16B per lane; LDS dest = wave-uniform base + lane*16
DEV void cp16(void* lds, const void* g) {
  __builtin_amdgcn_global_load_lds(
      (const __attribute__((address_space(1))) unsigned int*)g,
      (__attribute__((address_space(3))) unsigned int*)lds, 16, 0, 0);
}

// XCD-aware bijective swizzle; requires gridDim.x % 8 == 0
DEV int xcd_swz() {
  int bid = blockIdx.x;
  int cpx = gridDim.x >> 3;
  return (bid & 7) * cpx + (bid >> 3);
}

// dims: B=256, N=77, D=768, K=16, Dn=768, HID=512, L=2

// ---------------- weight transposes+casts in one launch (Wv, We1, Wg) ----------------
__global__ __launch_bounds__(256) void tcast_all(const float* __restrict__ Wv,
                                                 const float* __restrict__ We1,
                                                 const float* __restrict__ Wg,
                                                 u16* __restrict__ WvT,
                                                 u16* __restrict__ We1T,
                                                 u16* __restrict__ WgT) {
  __shared__ float tile[32][33];
  const float* src; u16* dst; int C;
  switch (blockIdx.z) {
    case 0: src = Wv;           dst = WvT;           C = 768; break;
    case 1: src = We1;          dst = We1T;          C = 512; break;
    case 2: src = We1 + 393216; dst = We1T + 393216; C = 512; break;
    case 3: src = Wg;           dst = WgT;           C = 768; break;
    default: src = Wg + 589824; dst = WgT + 589824;  C = 768; break;
  }
  int r0 = blockIdx.y * 32, c0 = blockIdx.x * 32;
  if (c0 >= C) return;
  int tr = threadIdx.x >> 5, tc = threadIdx.x & 31;
#pragma unroll
  for (int rr = 0; rr < 4; ++rr)
    tile[tr + rr * 8][tc] = src[(size_t)(r0 + tr + rr * 8) * C + c0 + tc];
  __syncthreads();
#pragma unroll
  for (int rr = 0; rr < 4; ++rr)
    dst[(size_t)(c0 + tr + rr * 8) * 768 + r0 + tc] = f2bf(tile[tc][tr + rr * 8]);
}

// ---------------- Q projection, single launch: Q[k,d] = nq[k]·Wq[:,d] + bq[d] ----------------
// grid 48; each block covers 256 consecutive d for one k (768 = 3*256, no k straddle).
__global__ __launch_bounds__(256) void q_kernel(const float* __restrict__ nq,
                                                const float* __restrict__ Wq,
                                                const float* __restrict__ bq,
                                                float* __restrict__ Qf) {
  int gid = blockIdx.x * 256 + threadIdx.x;  // 0..12287
  int k = gid / 768, d = gid % 768;
  const float* nr = nq + k * 768;
  const float* wp = Wq + d;
  float s0 = 0.f, s1 = 0.f, s2 = 0.f, s3 = 0.f;
#pragma unroll 4
  for (int c = 0; c < 768; c += 4) {
    s0 += nr[c + 0] * wp[(size_t)(c + 0) * 768];
    s1 += nr[c + 1] * wp[(size_t)(c + 1) * 768];
    s2 += nr[c + 2] * wp[(size_t)(c + 2) * 768];
    s3 += nr[c + 3] * wp[(size_t)(c + 3) * 768];
  }
  Qf[gid] = (s0 + s1) + (s2 + s3) + bq[d];
}

// ---------------- PT[k,c] = sum_d Wk[c,d]*Q[k,d] (bf16); qb[k] = Q[k]·bk ----------------
__global__ __launch_bounds__(256) void pt_kernel(const float* __restrict__ Qf,
                                                 const float* __restrict__ Wk,
                                                 const float* __restrict__ bk,
                                                 u16* __restrict__ PT16,
                                                 float* __restrict__ qb) {
  int t = threadIdx.x;
  if (blockIdx.x == 48) {
    int k = t >> 4, j = t & 15;
    const float* q = Qf + k * 768 + j * 48;
    const float* bp = bk + j * 48;
    float s = 0.f;
#pragma unroll
    for (int d = 0; d < 48; d += 4) {
      f32x4 qv = *(const f32x4*)&q[d];
      f32x4 bv4 = *(const f32x4*)&bp[d];
      s += qv[0] * bv4[0] + qv[1] * bv4[1] + qv[2] * bv4[2] + qv[3] * bv4[3];
    }
#pragma unroll
    for (int off = 1; off < 16; off <<= 1) s += __shfl_xor(s, off);
    if (j == 0) qb[k] = s;
    return;
  }
  int gid = blockIdx.x * 256 + t;
  int c = gid >> 4, k = gid & 15;  // 16 threads share row c -> broadcast reads of Wk
  const float* wr = Wk + (size_t)c * 768;
  const float* q = Qf + k * 768;
  float s = 0.f;
  for (int d = 0; d < 768; d += 4) {
    f32x4 wv = *(const f32x4*)&wr[d];
    f32x4 qv = *(const f32x4*)&q[d];
    s += wv[0] * qv[0] + wv[1] * qv[1] + wv[2] * qv[2] + wv[3] * qv[3];
  }
  PT16[k * 768 + c] = f2bf(s);
}

// ---------------- scores via MFMA directly from f32 w (cast in-register) ----------------
__global__ __launch_bounds__(256) void score2(const float* __restrict__ w,
                                              const u16* __restrict__ PT16,
                                              const float* __restrict__ qb,
                                              const int* __restrict__ mask,
                                              float* __restrict__ Sout) {
  __shared__ u16 Ps[16 * 776];
  int t = threadIdx.x, wave = t >> 6, lane = t & 63, l16 = lane & 15, quad = lane >> 4;
  int m0 = blockIdx.x * 64;
#pragma unroll
  for (int r = 0; r < 6; ++r) {
    int idx = t + 256 * r;
    int row = idx / 96, c8 = idx % 96;
    *(short8*)&Ps[row * 776 + c8 * 8] = *(const short8*)&PT16[row * 768 + c8 * 8];
  }
  __syncthreads();
  int row = m0 + wave * 16 + l16;
  const float* ap = w + (size_t)row * 768 + quad * 8;
  f32x4 acc = {0.f, 0.f, 0.f, 0.f};
#pragma unroll
  for (int it = 0; it < 24; ++it) {
    f32x4 a0 = *(const f32x4*)(ap + it * 32);
    f32x4 a1 = *(const f32x4*)(ap + it * 32 + 4);
    short8 fa;
#pragma unroll
    for (int e = 0; e < 4; ++e) { fa[e] = (short)f2bf(a0[e]); fa[e + 4] = (short)f2bf(a1[e]); }
    short8 fb = *(const short8*)&Ps[l16 * 776 + it * 32 + quad * 8];
    acc = __builtin_amdgcn_mfma_f32_16x16x32_bf16(fa, fb, acc, 0, 0, 0);
  }
  float qv = qb[l16];
  const float scale = 0.1020620726159658f;  // (768/8)^-0.5
#pragma unroll
  for (int r = 0; r < 4; ++r) {
    int orow = m0 + wave * 16 + quad * 4 + r;
    float s = (acc[r] + qv) * scale;
    if (mask[orow] == 0) s = -3.402823466e38f;  // finfo(f32).min
    float mx = s;
#pragma unroll
    for (int off = 1; off < 16; off <<= 1) mx = fmaxf(mx, __shfl_xor(mx, off));
    float e = __expf(s - mx);
    float sm = e;
#pragma unroll
    for (int off = 1; off < 16; off <<= 1) sm += __shfl_xor(sm, off);
    Sout[(size_t)orow * 16 + l16] = e / sm;
  }
}

// ---------------- U[b] = S[b]^T @ w[b] (f32 direct); sk[b,k] = colsum S. grid (256,3) ----------------
__global__ __launch_bounds__(256) void u_kernel(const float* __restrict__ Sg,
                                                const float* __restrict__ w,
                                                u16* __restrict__ U16,
                                                float* __restrict__ sk) {
  __shared__ float Ss[1232];
  int b = blockIdx.x, t = threadIdx.x;
  int d = blockIdx.y * 256 + t;
#pragma unroll
  for (int r = 0; r < 5; ++r) {
    int idx = t + 256 * r;
    if (idx < 1232) Ss[idx] = Sg[(size_t)b * 1232 + idx];
  }
  __syncthreads();
  float a[16];
#pragma unroll
  for (int k = 0; k < 16; ++k) a[k] = 0.f;
  const float* wp = w + (size_t)b * 59136;  // 77*768
  for (int n = 0; n < 77; ++n) {
    float g = wp[(size_t)n * 768 + d];
    const float* sr = &Ss[n * 16];
#pragma unroll
    for (int k = 0; k < 16; ++k) a[k] += sr[k] * g;
  }
#pragma unroll
  for (int k = 0; k < 16; ++k)
    U16[(size_t)b * 12288 + (size_t)k * 768 + d] = f2bf(a[k]);
  if (blockIdx.y == 0 && t < 16) {
    float s = 0.f;
    for (int n = 0; n < 77; ++n) s += Ss[n * 16 + t];
    sk[b * 16 + t] = s;
  }
}

// 64x128 staging, 3-deep
#define STAGE3(KOFF, BI)                          \
  do {                                            \
    cp16(AsW + (BI) * 2048, Ap + (KOFF));         \
    cp16(BsW1 + (BI) * 4096, Bp1 + (KOFF));       \
    cp16(BsW2 + (BI) * 4096, Bp2 + (KOFF));       \
  } while (0)

// ---------------- V = U @ WvT + sk*bv, gate blend. 3-deep counted-vmcnt pipeline ----------------
__global__ __launch_bounds__(256) void vgemm(const u16* __restrict__ A,
                                             const u16* __restrict__ BT,
                                             const float* __restrict__ skp,
                                             const float* __restrict__ bv,
                                             const float* __restrict__ nq,
                                             const float* __restrict__ gatep,
                                             float* __restrict__ V32,
                                             u16* __restrict__ V16) {
  __shared__ u16 As[3 * 64 * 32];
  __shared__ u16 Bs[3 * 128 * 32];
  int swz = xcd_swz();
  int mi = swz / 6, ni = swz % 6;
  int m0 = mi * 64, n0 = ni * 128;
  int t = threadIdx.x;
  int wave = t >> 6, lane = t & 63, l16 = lane & 15, quad = lane >> 4;
  int ra = wave * 16 + (lane >> 2);
  int rb1 = wave * 32 + (lane >> 2);
  int rb2 = rb1 + 16;
  int cslot = lane & 3;
  int cga = (cslot ^ ((ra >> 1) & 3)) * 8;
  int cgb1 = (cslot ^ ((rb1 >> 1) & 3)) * 8;
  int cgb2 = (cslot ^ ((rb2 >> 1) & 3)) * 8;

  const u16* Ap = A + (size_t)(m0 + ra) * 768 + cga;
  const u16* Bp1 = BT + (size_t)(n0 + rb1) * 768 + cgb1;
  const u16* Bp2 = BT + (size_t)(n0 + rb2) * 768 + cgb2;
  u16* AsW = &As[(wave * 16) * 32];
  u16* BsW1 = &Bs[(wave * 32) * 32];
  u16* BsW2 = &Bs[(wave * 32 + 16) * 32];

  f32x4 zero4 = {0.f, 0.f, 0.f, 0.f};
  f32x4 acc[4][2];
#pragma unroll
  for (int i = 0; i < 4; ++i) { acc[i][0] = zero4; acc[i][1] = zero4; }

  STAGE3(0, 0); STAGE3(32, 1); STAGE3(64, 2);

  int bi = 0;
  for (int k0 = 0; k0 < 768; k0 += 32) {
    int rem = (768 - 32 - k0) >> 5;
    if (rem >= 2)      asm volatile("s_waitcnt vmcnt(6)" ::: "memory");
    else if (rem == 1) asm volatile("s_waitcnt vmcnt(3)" ::: "memory");
    else               asm volatile("s_waitcnt vmcnt(0)" ::: "memory");
    asm volatile("s_barrier" ::: "memory");
    const u16* Ab = &As[bi * 2048];
    const u16* Bb = &Bs[bi * 4096];
    short8 fa[4], fb[2];
#pragma unroll
    for (int i = 0; i < 4; ++i) {
      int R = i * 16 + l16;
      fa[i] = *(const short8*)&Ab[R * 32 + (quad ^ ((R >> 1) & 3)) * 8];
    }
#pragma unroll
    for (int j = 0; j < 2; ++j) {
      int R = wave * 32 + j * 16 + l16;
      fb[j] = *(const short8*)&Bb[R * 32 + (quad ^ ((R >> 1) & 3)) * 8];
    }
#pragma unroll
    for (int i = 0; i < 4; ++i)
#pragma unroll
      for (int j = 0; j < 2; ++j)
        acc[i][j] = __builtin_amdgcn_mfma_f32_16x16x32_bf16(fa[i], fb[j], acc[i][j], 0, 0, 0);
    asm volatile("s_barrier" ::: "memory");
    if (k0 + 96 < 768) STAGE3(k0 + 96, bi);
    bi = bi + 1; if (bi == 3) bi = 0;
  }

  float gv = gatep[0];
  float g = 1.f / (1.f + __expf(-gv)), og = 1.f - g;
  int narr[2]; float bvj[2];
#pragma unroll
  for (int j = 0; j < 2; ++j) {
    narr[j] = n0 + wave * 32 + j * 16 + l16;
    bvj[j] = bv[narr[j]];
  }
#pragma unroll
  for (int i = 0; i < 4; ++i)
#pragma unroll
    for (int r = 0; r < 4; ++r) {
      int m = m0 + i * 16 + quad * 4 + r;
      float skv = skp[m];
      size_t mrow = (size_t)m * 768;
      const float* nqr = nq + (m & 15) * 768;
#pragma unroll
      for (int j = 0; j < 2; ++j) {
        float val = acc[i][j][r] + skv * bvj[j];
        float v = og * val + g * nqr[narr[j]];
        V32[mrow + narr[j]] = v;
        V16[mrow + narr[j]] = f2bf(v);
      }
    }
}

// ---------------- small MFMA GEMM 64x128, dual-output, 3-deep counted-vmcnt pipeline ----------------
__global__ __launch_bounds__(256) void gemm16s(const u16* __restrict__ A,
                                               const u16* __restrict__ BT0,
                                               const float* __restrict__ bias0,
                                               u16* __restrict__ C0, int N0, int ntA,
                                               const u16* __restrict__ BT1,
                                               const float* __restrict__ bias1,
                                               u16* __restrict__ C1, int N1, int ntB,
                                               int K) {
  __shared__ u16 As[3 * 64 * 32];
  __shared__ u16 Bs[3 * 128 * 32];
  int nt = ntA + ntB;
  int swz = xcd_swz();
  int mi = swz / nt, ni = swz % nt;
  const u16* BT; const float* bias; u16* C; int N, n0;
  if (ni < ntA) { BT = BT0; bias = bias0; C = C0; N = N0; n0 = ni * 128; }
  else          { BT = BT1; bias = bias1; C = C1; N = N1; n0 = (ni - ntA) * 128; }
  int m0 = mi * 64;
  int t = threadIdx.x;
  int wave = t >> 6, lane = t & 63, l16 = lane & 15, quad = lane >> 4;
  int ra = wave * 16 + (lane >> 2);
  int rb1 = wave * 32 + (lane >> 2);
  int rb2 = rb1 + 16;
  int cslot = lane & 3;
  int cga = (cslot ^ ((ra >> 1) & 3)) * 8;
  int cgb1 = (cslot ^ ((rb1 >> 1) & 3)) * 8;
  int cgb2 = (cslot ^ ((rb2 >> 1) & 3)) * 8;

  const u16* Ap = A + (size_t)(m0 + ra) * K + cga;
  const u16* Bp1 = BT + (size_t)(n0 + rb1) * K + cgb1;
  const u16* Bp2 = BT + (size_t)(n0 + rb2) * K + cgb2;
  u16* AsW = &As[(wave * 16) * 32];
  u16* BsW1 = &Bs[(wave * 32) * 32];
  u16* BsW2 = &Bs[(wave * 32 + 16) * 32];

  f32x4 zero4 = {0.f, 0.f, 0.f, 0.f};
  f32x4 acc[4][2];
#pragma unroll
  for (int i = 0; i < 4; ++i) { acc[i][0] = zero4; acc[i][1] = zero4; }

  STAGE3(0, 0); STAGE3(32, 1); STAGE3(64, 2);

  int bi = 0;
  for (int k0 = 0; k0 < K; k0 += 32) {
    int rem = (K - 32 - k0) >> 5;
    if (rem >= 2)      asm volatile("s_waitcnt vmcnt(6)" ::: "memory");
    else if (rem == 1) asm volatile("s_waitcnt vmcnt(3)" ::: "memory");
    else               asm volatile("s_waitcnt vmcnt(0)" ::: "memory");
    asm volatile("s_barrier" ::: "memory");
    const u16* Ab = &As[bi * 2048];
    const u16* Bb = &Bs[bi * 4096];
    short8 fa[4], fb[2];
#pragma unroll
    for (int i = 0; i < 4; ++i) {
      int R = i * 16 + l16;
      fa[i] = *(const short8*)&Ab[R * 32 + (quad ^ ((R >> 1) & 3)) * 8];
    }
#pragma unroll
    for (int j = 0; j < 2; ++j) {
      int R = wave * 32 + j * 16 + l16;
      fb[j] = *(const short8*)&Bb[R * 32 + (quad ^ ((R >> 1) & 3)) * 8];
    }
#pragma unroll
    for (int i = 0; i < 4; ++i)
#pragma unroll
      for (int j = 0; j < 2; ++j)
        acc[i][j] = __builtin_amdgcn_mfma_f32_16x16x32_bf16(fa[i], fb[j], acc[i][j], 0, 0, 0);
    asm volatile("s_barrier" ::: "memory");
    if (k0 + 96 < K) STAGE3(k0 + 96, bi);
    bi = bi + 1; if (bi == 3) bi = 0;
  }

  int narr[2]; float bvj[2];
#pragma unroll
  for (int j = 0; j < 2; ++j) {
    narr[j] = n0 + wave * 32 + j * 16 + l16;
    bvj[j] = bias ? bias[narr[j]] : 0.f;
  }
#pragma unroll
  for (int i = 0; i < 4; ++i)
#pragma unroll
    for (int r = 0; r < 4; ++r) {
      size_t mrow = (size_t)(m0 + i * 16 + quad * 4 + r) * N;
#pragma unroll
      for (int j = 0; j < 2; ++j)
        C[mrow + narr[j]] = f2bf(acc[i][j][r] + bvj[j]);
    }
}

// 128x128 staging, 2-deep double buffer
#define STG128(BI, KOFF)                                    \
  do {                                                      \
    cp16(&As[(BI) * 4096 + (wave * 32) * 32],      Ap1 + (KOFF)); \
    cp16(&As[(BI) * 4096 + (wave * 32 + 16) * 32], Ap2 + (KOFF)); \
    cp16(&Bs[(BI) * 4096 + (wave * 32) * 32],      Bp1 + (KOFF)); \
    cp16(&Bs[(BI) * 4096 + (wave * 32 + 16) * 32], Bp2 + (KOFF)); \
  } while (0)

// ---------------- big MFMA GEMM 128x128, dual-output, counted-vmcnt dbuf ----------------
// Use ONLY for launches with grid >= ~1.5 * 256 blocks (parallelism law).
__global__ __launch_bounds__(256) void gemm128(const u16* __restrict__ A,
                                               const u16* __restrict__ BT0,
                                               const float* __restrict__ bias0,
                                               u16* __restrict__ C0, int N0, int ntA,
                                               const u16* __restrict__ BT1,
                                               const float* __restrict__ bias1,
                                               u16* __restrict__ C1, int N1, int ntB,
                                               int K) {
  __shared__ u16 As[2 * 128 * 32];
  __shared__ u16 Bs[2 * 128 * 32];
  int nt = ntA + ntB;
  int swz = xcd_swz();
  int mi = swz / nt, ni = swz % nt;
  const u16* BT; const float* bias; u16* C; int N, n0;
  if (ni < ntA) { BT = BT0; bias = bias0; C = C0; N = N0; n0 = ni * 128; }
  else          { BT = BT1; bias = bias1; C = C1; N = N1; n0 = (ni - ntA) * 128; }
  int m0 = mi * 128;
  int t = threadIdx.x;
  int wave = t >> 6, lane = t & 63, l16 = lane & 15, quad = lane >> 4;
  int wrow = (wave >> 1) * 64, wcol = (wave & 1) * 64;
  int r1 = wave * 32 + (lane >> 2);
  int r2 = r1 + 16;
  int cslot = lane & 3;
  int cg1 = (cslot ^ ((r1 >> 1) & 3)) * 8;
  int cg2 = (cslot ^ ((r2 >> 1) & 3)) * 8;

  const u16* Ap1 = A + (size_t)(m0 + r1) * K + cg1;
  const u16* Ap2 = A + (size_t)(m0 + r2) * K + cg2;
  const u16* Bp1 = BT + (size_t)(n0 + r1) * K + cg1;
  const u16* Bp2 = BT + (size_t)(n0 + r2) * K + cg2;

  f32x4 zero4 = {0.f, 0.f, 0.f, 0.f};
  f32x4 acc[4][4];
#pragma unroll
  for (int i = 0; i < 4; ++i)
#pragma unroll
    for (int j = 0; j < 4; ++j) acc[i][j] = zero4;

  STG128(0, 0); STG128(1, 32);

  int cur = 0;
  for (int k0 = 0; k0 < K; k0 += 32) {
    if (k0 + 32 < K) asm volatile("s_waitcnt vmcnt(4)" ::: "memory");
    else             asm volatile("s_waitcnt vmcnt(0)" ::: "memory");
    asm volatile("s_barrier" ::: "memory");
    const u16* Ab = &As[cur * 4096];
    const u16* Bb = &Bs[cur * 4096];
    short8 fa[4], fb[4];
#pragma unroll
    for (int i = 0; i < 4; ++i) {
      int R = wrow + i * 16 + l16;
      fa[i] = *(const short8*)&Ab[R * 32 + (quad ^ ((R >> 1) & 3)) * 8];
    }
#pragma unroll
    for (int j = 0; j < 4; ++j) {
      int R = wcol + j * 16 + l16;
      fb[j] = *(const short8*)&Bb[R * 32 + (quad ^ ((R >> 1) & 3)) * 8];
    }
#pragma unroll
    for (int i = 0; i < 4; ++i)
#pragma unroll
      for (int j = 0; j < 4; ++j)
        acc[i][j] = __builtin_amdgcn_mfma_f32_16x16x32_bf16(fa[i], fb[j], acc[i][j], 0, 0, 0);
    asm volatile("s_barrier" ::: "memory");
    if (k0 + 64 < K) STG128(cur, k0 + 64);
    cur ^= 1;
  }

  int narr[4]; float bvj[4];
#pragma unroll
  for (int j = 0; j < 4; ++j) {
    narr[j] = n0 + wcol + j * 16 + l16;
    bvj[j] = bias ? bias[narr[j]] : 0.f;
  }
#pragma unroll
  for (int i = 0; i < 4; ++i)
#pragma unroll
    for (int r = 0; r < 4; ++r) {
      size_t mrow = (size_t)(m0 + wrow + i * 16 + quad * 4 + r) * N;
#pragma unroll
      for (int j = 0; j < 4; ++j)
        C[mrow + narr[j]] = f2bf(acc[i][j][r] + bvj[j]);
    }
}

// ---------------- edge logits (+softmax); grid (256 batches, 2 i-halves) ----------------
__global__ __launch_bounds__(256) void edge_kernel(const u16* __restrict__ HIJ,
                                                   const float* __restrict__ be1,
                                                   const float* __restrict__ We2,
                                                   const float* __restrict__ be2v,
                                                   float* __restrict__ Aout,
                                                   float* __restrict__ Eout) {
  __shared__ float hiS[8 * 516];
  __shared__ float hjS[16 * 516];
  __shared__ float be1s[512];
  __shared__ float w2s[512];
  int b = blockIdx.x, ih = blockIdx.y, t = threadIdx.x;
  be1s[t] = be1[t]; be1s[t + 256] = be1[t + 256];
  w2s[t] = We2[t];  w2s[t + 256] = We2[t + 256];

#pragma unroll
  for (int r = 0; r < 6; ++r) {
    int idx = t + 256 * r;  // 0..1535 short8 chunks
    const u16* src;
    float* dst;
    if (idx < 512) {
      int row = idx >> 6, c8 = idx & 63;
      src = &HIJ[(size_t)(b * 16 + ih * 8 + row) * 1024 + c8 * 8];
      dst = &hiS[row * 516 + c8 * 8];
    } else {
      int k = idx - 512;
      int row = k >> 6, c8 = k & 63;
      src = &HIJ[(size_t)(b * 16 + row) * 1024 + 512 + c8 * 8];
      dst = &hjS[row * 516 + c8 * 8];
    }
    short8 hv = *(const short8*)src;
    f32x4 l0, l1;
#pragma unroll
    for (int ee = 0; ee < 4; ++ee) { l0[ee] = bf2f((u16)hv[ee]); l1[ee] = bf2f((u16)hv[ee + 4]); }
    *(f32x4*)dst = l0;
    *(f32x4*)(dst + 4) = l1;
  }
  __syncthreads();

  int i_loc = t >> 5, j = (t >> 1) & 15, hh = t & 1;
  const float* hi = &hiS[i_loc * 516 + hh * 256];
  const float* hj = &hjS[j * 516 + hh * 256];
  const float* b1 = &be1s[hh * 256];
  const float* w2 = &w2s[hh * 256];
  float e = 0.f;
#pragma unroll 2
  for (int h4 = 0; h4 < 64; ++h4) {
    f32x4 hv = *(const f32x4*)&hi[h4 * 4];
    f32x4 jv = *(const f32x4*)&hj[h4 * 4];
    f32x4 bv = *(const f32x4*)&b1[h4 * 4];
    f32x4 wv = *(const f32x4*)&w2[h4 * 4];
#pragma unroll
    for (int ee = 0; ee < 4; ++ee)
      e += fmaxf(hv[ee] + jv[ee] + bv[ee], 0.f) * wv[ee];
  }
  e += __shfl_xor(e, 1);  // combine the two h-halves
  e += be2v[0];

  int pair = (ih * 8 + i_loc) * 16 + j;
  if (Aout) {
    float mx = e;
#pragma unroll
    for (int off = 2; off < 32; off <<= 1) mx = fmaxf(mx, __shfl_xor(mx, off));
    float ex = __expf(e - mx);
    float sm = ex;
#pragma unroll
    for (int off = 2; off < 32; off <<= 1) sm += __shfl_xor(sm, off);
    if (hh == 0) Aout[(size_t)b * 256 + pair] = ex / sm;
  }
  if (Eout && hh == 0) Eout[(size_t)b * 256 + pair] = e;
}

// ---------------- GNN combine: V += relu(A @ G); grid (256 batches, 3 d-chunks) ----------------
// Final layer (Vout != null): V32 store skipped (dead afterward).
__global__ __launch_bounds__(256) void combine_kernel(const float* __restrict__ Aws,
                                                      const u16* __restrict__ G,
                                                      float* __restrict__ V32,
                                                      u16* __restrict__ V16,
                                                      float* __restrict__ Vout) {
  __shared__ float Gs[16 * 260];
  __shared__ float As[256];
  int b = blockIdx.x, yc = blockIdx.y, t = threadIdx.x;
#pragma unroll
  for (int r = 0; r < 2; ++r) {
    int idx = t + 256 * r;          // 512 short8 chunks (16 rows x 32)
    int row = idx >> 5, c8 = idx & 31;
    short8 gv8 = *(const short8*)&G[(size_t)(b * 16 + row) * 768 + yc * 256 + c8 * 8];
    f32x4 l0, l1;
#pragma unroll
    for (int ee = 0; ee < 4; ++ee) { l0[ee] = bf2f((u16)gv8[ee]); l1[ee] = bf2f((u16)gv8[ee + 4]); }
    *(f32x4*)&Gs[row * 260 + c8 * 8] = l0;
    *(f32x4*)&Gs[row * 260 + c8 * 8 + 4] = l1;
  }
  As[t] = Aws[(size_t)b * 256 + t];
  __syncthreads();
  int d = yc * 256 + t;
  float gv[16];
#pragma unroll
  for (int j = 0; j < 16; ++j) gv[j] = Gs[j * 260 + t];
#pragma unroll
  for (int i = 0; i < 16; ++i) {
    float msg = 0.f;
#pragma unroll
    for (int j = 0; j < 16; ++j) msg += As[i * 16 + j] * gv[j];
    size_t idx = (size_t)b * 12288 + (size_t)i * 768 + d;
    float v = V32[idx] + fmaxf(msg, 0.f);
    if (Vout) { Vout[idx] = v; }
    else      { V32[idx] = v; }
    V16[idx] = f2bf(v);
  }
}

extern "C" void kernel_launch(void* const* d_in, const int* in_sizes, int n_in,
                              void* d_out, int out_size, void* d_ws, size_t ws_size,
                              hipStream_t stream) {
  const float* w    = (const float*)d_in[0];   // [256,77,768]
  const int*   mask = (const int*)d_in[1];     // [256,77]
  const float* nq   = (const float*)d_in[2];   // [1,16,768]
  const float* Wq   = (const float*)d_in[3];
  const float* bq   = (const float*)d_in[4];
  const float* Wk   = (const float*)d_in[5];
  const float* bk   = (const float*)d_in[6];
  const float* Wv   = (const float*)d_in[7];
  const float* bv   = (const float*)d_in[8];
  const float* We1  = (const float*)d_in[9];   // [1536,512]
  const float* be1  = (const float*)d_in[10];
  const float* We2  = (const float*)d_in[11];  // [512,1]
  const float* be2  = (const float*)d_in[12];
  const float* gate = (const float*)d_in[13];
  const float* Wg   = (const float*)d_in[14];  // [2,768,768]
  const float* bg   = (const float*)d_in[15];  // [2,768]

  // workspace
  float* ws    = (float*)d_ws;
  float* V32   = ws;                    // 3,145,728 f
  float* Aws   = V32 + 3145728;         // 65,536 f
  float* Qf    = Aws + 65536;           // 12,288 f
  float* qb    = Qf + 12288;            // 16 f
  float* sk    = qb + 16;               // 4,096 f
  u16* PT16    = (u16*)(sk + 4096);     // 12,288 u16
  u16* WvT     = PT16 + 12288;          // 589,824
  u16* We1T    = WvT + 589824;          // 786,432
  u16* WgT     = We1T + 786432;         // 1,179,648
  u16* V16     = WgT + 1179648;         // 3,145,728
  u16* U16     = V16 + 3145728;         // 3,145,728
  u16* HIJ     = U16 + 3145728;         // 4,194,304
  u16* Gws     = HIJ + 4194304;         // 3,145,728

  float* out  = (float*)d_out;
  float* Sout = out;                       // [256,77,16]
  float* Vout = out + 315392;              // [256,16,768]
  float* Eout = out + 315392 + 3145728;    // [256,16,16]

  dim3 blk(256);

  // prep: weights -> bf16 [n][k]; Q; PT/qb
  tcast_all<<<dim3(24, 24, 5), blk, 0, stream>>>(Wv, We1, Wg, WvT, We1T, WgT);
  q_kernel<<<48, blk, 0, stream>>>(nq, Wq, bq, Qf);
  pt_kernel<<<49, blk, 0, stream>>>(Qf, Wk, bk, PT16, qb);

  // scores directly from f32 w (cast in-register); softmax -> Sout
  score2<<<308, blk, 0, stream>>>(w, PT16, qb, mask, Sout);

  // U = S^T @ w (per batch, f32) + colsums; V = U @ WvT + sk*bv, gate blend
  u_kernel<<<dim3(256, 3), blk, 0, stream>>>(Sout, w, U16, sk);
  vgemm<<<384, blk, 0, stream>>>(U16, WvT, sk, bv, nq, gate, V32, V16);

  // fused: pre-GNN edge gemm (HIJ, 8 n-tiles) + GNN layer-0 gemm (Gws, 6 n-tiles)
  // 128x128 tile: grid 448 >= 1.75 blocks/CU, density win without parallelism loss
  gemm128<<<448, blk, 0, stream>>>(V16, We1T, nullptr, HIJ, 1024, 8,
                                   WgT, bg, Gws, 768, 6, 768);
  // layer-0 edge (A) + combine
  edge_kernel<<<dim3(256, 2), blk, 0, stream>>>(HIJ, be1, We2, be2, Aws, (float*)nullptr);
  combine_kernel<<<dim3(256, 3), blk, 0, stream>>>(Aws, Gws, V32, V16, (float*)nullptr);

  // GNN layer 1 (64x128 tile keeps grid at 384)
  gemm16s<<<384, blk, 0, stream>>>(V16, WgT + 589824, bg + 768, Gws, 768, 6,
                                   WgT + 589824, bg + 768, Gws, 768, 0, 768);
  combine_kernel<<<dim3(256, 3), blk, 0, stream>>>(Aws, Gws, V32, V16, Vout);

  // post-GNN edge logits -> E (64x128 tile keeps grid at 512)
  gemm16s<<<512, blk, 0, stream>>>(V16, We1T, nullptr, HIJ, 1024, 8,
                                   We1T, nullptr, HIJ, 1024, 0, 768);
  edge_kernel<<<dim3(256, 2), blk, 0, stream>>>(HIJ, be1, We2, be2, (float*)nullptr, Eout);
}

// Round 9
// 305.232 us; speedup vs baseline: 1.0360x; 1.0360x over previous
//
#include <hip/hip_runtime.h>

typedef unsigned short u16;
typedef __attribute__((ext_vector_type(8))) short short8;
typedef __attribute__((ext_vector_type(4))) float f32x4;

#define DEV static __device__ __forceinline__

DEV float bf2f(u16 u) { return __uint_as_float(((unsigned)u) << 16); }
DEV u16 f2bf(float f) {
  unsigned u = __float_as_uint(f);
  return (u16)((u + 0x7fffu + ((u >> 16) & 1u)) >> 16);
}

// async global->LDS, 16B per lane; LDS dest = wave-uniform base + lane*16
DEV void cp16(void* lds, const void* g) {
  __builtin_amdgcn_global_load_lds(
      (const __attribute__((address_space(1))) unsigned int*)g,
      (__attribute__((address_space(3))) unsigned int*)lds, 16, 0, 0);
}

// XCD-aware bijective swizzle; requires gridDim.x % 8 == 0
DEV int xcd_swz() {
  int bid = blockIdx.x;
  int cpx = gridDim.x >> 3;
  return (bid & 7) * cpx + (bid >> 3);
}

// dims: B=256, N=77, D=768, K=16, Dn=768, HID=512, L=2

// ---------------- weight transposes+casts in one launch (Wv, We1, Wg) ----------------
__global__ __launch_bounds__(256) void tcast_all(const float* __restrict__ Wv,
                                                 const float* __restrict__ We1,
                                                 const float* __restrict__ Wg,
                                                 u16* __restrict__ WvT,
                                                 u16* __restrict__ We1T,
                                                 u16* __restrict__ WgT) {
  __shared__ float tile[32][33];
  const float* src; u16* dst; int C;
  switch (blockIdx.z) {
    case 0: src = Wv;           dst = WvT;           C = 768; break;
    case 1: src = We1;          dst = We1T;          C = 512; break;
    case 2: src = We1 + 393216; dst = We1T + 393216; C = 512; break;
    case 3: src = Wg;           dst = WgT;           C = 768; break;
    default: src = Wg + 589824; dst = WgT + 589824;  C = 768; break;
  }
  int r0 = blockIdx.y * 32, c0 = blockIdx.x * 32;
  if (c0 >= C) return;
  int tr = threadIdx.x >> 5, tc = threadIdx.x & 31;
#pragma unroll
  for (int rr = 0; rr < 4; ++rr)
    tile[tr + rr * 8][tc] = src[(size_t)(r0 + tr + rr * 8) * C + c0 + tc];
  __syncthreads();
#pragma unroll
  for (int rr = 0; rr < 4; ++rr)
    dst[(size_t)(c0 + tr + rr * 8) * 768 + r0 + tc] = f2bf(tile[tc][tr + rr * 8]);
}

// ---------------- Q projection, split-K stage 1 ----------------
__global__ __launch_bounds__(256) void q_part(const float* __restrict__ nq,
                                              const float* __restrict__ Wq,
                                              float* __restrict__ Qpart) {
  int gid = blockIdx.x * 256 + threadIdx.x;  // 0..12287
  int s = blockIdx.y;
  int k = gid / 768, d = gid % 768;
  const float* nr = nq + k * 768 + s * 96;
  const float* wp = Wq + (size_t)(s * 96) * 768 + d;
  float s0 = 0.f, s1 = 0.f, s2 = 0.f, s3 = 0.f;
#pragma unroll
  for (int c = 0; c < 96; c += 4) {
    s0 += nr[c + 0] * wp[(size_t)(c + 0) * 768];
    s1 += nr[c + 1] * wp[(size_t)(c + 1) * 768];
    s2 += nr[c + 2] * wp[(size_t)(c + 2) * 768];
    s3 += nr[c + 3] * wp[(size_t)(c + 3) * 768];
  }
  Qpart[(size_t)s * 12288 + gid] = (s0 + s1) + (s2 + s3);
}

// ---------------- Q projection, stage 2: reduce + bias -> f32 Q ----------------
__global__ __launch_bounds__(256) void q_reduce(const float* __restrict__ Qpart,
                                                const float* __restrict__ bq,
                                                float* __restrict__ Qf) {
  int gid = blockIdx.x * 256 + threadIdx.x;  // 0..12287
  int d = gid % 768;
  float s = bq[d];
#pragma unroll
  for (int i = 0; i < 8; ++i) s += Qpart[(size_t)i * 12288 + gid];
  Qf[gid] = s;
}

// ---------------- PT[k,c] = sum_d Wk[c,d]*Q[k,d] (bf16); qb[k] = Q[k]·bk ----------------
__global__ __launch_bounds__(256) void pt_kernel(const float* __restrict__ Qf,
                                                 const float* __restrict__ Wk,
                                                 const float* __restrict__ bk,
                                                 u16* __restrict__ PT16,
                                                 float* __restrict__ qb) {
  int t = threadIdx.x;
  if (blockIdx.x == 48) {
    int k = t >> 4, j = t & 15;
    const float* q = Qf + k * 768 + j * 48;
    const float* bp = bk + j * 48;
    float s = 0.f;
#pragma unroll
    for (int d = 0; d < 48; d += 4) {
      f32x4 qv = *(const f32x4*)&q[d];
      f32x4 bv4 = *(const f32x4*)&bp[d];
      s += qv[0] * bv4[0] + qv[1] * bv4[1] + qv[2] * bv4[2] + qv[3] * bv4[3];
    }
#pragma unroll
    for (int off = 1; off < 16; off <<= 1) s += __shfl_xor(s, off);
    if (j == 0) qb[k] = s;
    return;
  }
  int gid = blockIdx.x * 256 + t;
  int c = gid >> 4, k = gid & 15;  // 16 threads share row c -> broadcast reads of Wk
  const float* wr = Wk + (size_t)c * 768;
  const float* q = Qf + k * 768;
  float s = 0.f;
  for (int d = 0; d < 768; d += 4) {
    f32x4 wv = *(const f32x4*)&wr[d];
    f32x4 qv = *(const f32x4*)&q[d];
    s += wv[0] * qv[0] + wv[1] * qv[1] + wv[2] * qv[2] + wv[3] * qv[3];
  }
  PT16[k * 768 + c] = f2bf(s);
}

// ---------------- scores via MFMA directly from f32 w (cast in-register) ----------------
__global__ __launch_bounds__(256) void score2(const float* __restrict__ w,
                                              const u16* __restrict__ PT16,
                                              const float* __restrict__ qb,
                                              const int* __restrict__ mask,
                                              float* __restrict__ Sout) {
  __shared__ u16 Ps[16 * 776];
  int t = threadIdx.x, wave = t >> 6, lane = t & 63, l16 = lane & 15, quad = lane >> 4;
  int m0 = blockIdx.x * 64;
#pragma unroll
  for (int r = 0; r < 6; ++r) {
    int idx = t + 256 * r;
    int row = idx / 96, c8 = idx % 96;
    *(short8*)&Ps[row * 776 + c8 * 8] = *(const short8*)&PT16[row * 768 + c8 * 8];
  }
  __syncthreads();
  int row = m0 + wave * 16 + l16;
  const float* ap = w + (size_t)row * 768 + quad * 8;
  f32x4 acc = {0.f, 0.f, 0.f, 0.f};
#pragma unroll
  for (int it = 0; it < 24; ++it) {
    f32x4 a0 = *(const f32x4*)(ap + it * 32);
    f32x4 a1 = *(const f32x4*)(ap + it * 32 + 4);
    short8 fa;
#pragma unroll
    for (int e = 0; e < 4; ++e) { fa[e] = (short)f2bf(a0[e]); fa[e + 4] = (short)f2bf(a1[e]); }
    short8 fb = *(const short8*)&Ps[l16 * 776 + it * 32 + quad * 8];
    acc = __builtin_amdgcn_mfma_f32_16x16x32_bf16(fa, fb, acc, 0, 0, 0);
  }
  float qv = qb[l16];
  const float scale = 0.1020620726159658f;  // (768/8)^-0.5
#pragma unroll
  for (int r = 0; r < 4; ++r) {
    int orow = m0 + wave * 16 + quad * 4 + r;
    float s = (acc[r] + qv) * scale;
    if (mask[orow] == 0) s = -3.402823466e38f;  // finfo(f32).min
    float mx = s;
#pragma unroll
    for (int off = 1; off < 16; off <<= 1) mx = fmaxf(mx, __shfl_xor(mx, off));
    float e = __expf(s - mx);
    float sm = e;
#pragma unroll
    for (int off = 1; off < 16; off <<= 1) sm += __shfl_xor(sm, off);
    Sout[(size_t)orow * 16 + l16] = e / sm;
  }
}

// ---------------- U[b] = S[b]^T @ w[b] (f32 direct); sk[b,k] = colsum S. grid (256,3) ----------------
__global__ __launch_bounds__(256) void u_kernel(const float* __restrict__ Sg,
                                                const float* __restrict__ w,
                                                u16* __restrict__ U16,
                                                float* __restrict__ sk) {
  __shared__ float Ss[1232];
  int b = blockIdx.x, t = threadIdx.x;
  int d = blockIdx.y * 256 + t;
#pragma unroll
  for (int r = 0; r < 5; ++r) {
    int idx = t + 256 * r;
    if (idx < 1232) Ss[idx] = Sg[(size_t)b * 1232 + idx];
  }
  __syncthreads();
  float a[16];
#pragma unroll
  for (int k = 0; k < 16; ++k) a[k] = 0.f;
  const float* wp = w + (size_t)b * 59136;  // 77*768
  for (int n = 0; n < 77; ++n) {
    float g = wp[(size_t)n * 768 + d];
    const float* sr = &Ss[n * 16];
#pragma unroll
    for (int k = 0; k < 16; ++k) a[k] += sr[k] * g;
  }
#pragma unroll
  for (int k = 0; k < 16; ++k)
    U16[(size_t)b * 12288 + (size_t)k * 768 + d] = f2bf(a[k]);
  if (blockIdx.y == 0 && t < 16) {
    float s = 0.f;
    for (int n = 0; n < 77; ++n) s += Ss[n * 16 + t];
    sk[b * 16 + t] = s;
  }
}

#define STAGE3(KOFF, BI)                          \
  do {                                            \
    cp16(AsW + (BI) * 2048, Ap + (KOFF));         \
    cp16(BsW1 + (BI) * 4096, Bp1 + (KOFF));       \
    cp16(BsW2 + (BI) * 4096, Bp2 + (KOFF));       \
  } while (0)

// ---------------- V = U @ WvT + sk*bv, gate blend. 3-deep counted-vmcnt pipeline ----------------
__global__ __launch_bounds__(256) void vgemm(const u16* __restrict__ A,
                                             const u16* __restrict__ BT,
                                             const float* __restrict__ skp,
                                             const float* __restrict__ bv,
                                             const float* __restrict__ nq,
                                             const float* __restrict__ gatep,
                                             float* __restrict__ V32,
                                             u16* __restrict__ V16) {
  __shared__ u16 As[3 * 64 * 32];
  __shared__ u16 Bs[3 * 128 * 32];
  int swz = xcd_swz();
  int mi = swz / 6, ni = swz % 6;
  int m0 = mi * 64, n0 = ni * 128;
  int t = threadIdx.x;
  int wave = t >> 6, lane = t & 63, l16 = lane & 15, quad = lane >> 4;
  int ra = wave * 16 + (lane >> 2);
  int rb1 = wave * 32 + (lane >> 2);
  int rb2 = rb1 + 16;
  int cslot = lane & 3;
  int cga = (cslot ^ ((ra >> 1) & 3)) * 8;
  int cgb1 = (cslot ^ ((rb1 >> 1) & 3)) * 8;
  int cgb2 = (cslot ^ ((rb2 >> 1) & 3)) * 8;

  const u16* Ap = A + (size_t)(m0 + ra) * 768 + cga;
  const u16* Bp1 = BT + (size_t)(n0 + rb1) * 768 + cgb1;
  const u16* Bp2 = BT + (size_t)(n0 + rb2) * 768 + cgb2;
  u16* AsW = &As[(wave * 16) * 32];
  u16* BsW1 = &Bs[(wave * 32) * 32];
  u16* BsW2 = &Bs[(wave * 32 + 16) * 32];

  f32x4 zero4 = {0.f, 0.f, 0.f, 0.f};
  f32x4 acc[4][2];
#pragma unroll
  for (int i = 0; i < 4; ++i) { acc[i][0] = zero4; acc[i][1] = zero4; }

  STAGE3(0, 0); STAGE3(32, 1); STAGE3(64, 2);

  int bi = 0;
  for (int k0 = 0; k0 < 768; k0 += 32) {
    int rem = (768 - 32 - k0) >> 5;
    if (rem >= 2)      asm volatile("s_waitcnt vmcnt(6)" ::: "memory");
    else if (rem == 1) asm volatile("s_waitcnt vmcnt(3)" ::: "memory");
    else               asm volatile("s_waitcnt vmcnt(0)" ::: "memory");
    asm volatile("s_barrier" ::: "memory");
    const u16* Ab = &As[bi * 2048];
    const u16* Bb = &Bs[bi * 4096];
    short8 fa[4], fb[2];
#pragma unroll
    for (int i = 0; i < 4; ++i) {
      int R = i * 16 + l16;
      fa[i] = *(const short8*)&Ab[R * 32 + (quad ^ ((R >> 1) & 3)) * 8];
    }
#pragma unroll
    for (int j = 0; j < 2; ++j) {
      int R = wave * 32 + j * 16 + l16;
      fb[j] = *(const short8*)&Bb[R * 32 + (quad ^ ((R >> 1) & 3)) * 8];
    }
#pragma unroll
    for (int i = 0; i < 4; ++i)
#pragma unroll
      for (int j = 0; j < 2; ++j)
        acc[i][j] = __builtin_amdgcn_mfma_f32_16x16x32_bf16(fa[i], fb[j], acc[i][j], 0, 0, 0);
    asm volatile("s_barrier" ::: "memory");
    if (k0 + 96 < 768) STAGE3(k0 + 96, bi);
    bi = bi + 1; if (bi == 3) bi = 0;
  }

  float gv = gatep[0];
  float g = 1.f / (1.f + __expf(-gv)), og = 1.f - g;
  int narr[2]; float bvj[2];
#pragma unroll
  for (int j = 0; j < 2; ++j) {
    narr[j] = n0 + wave * 32 + j * 16 + l16;
    bvj[j] = bv[narr[j]];
  }
#pragma unroll
  for (int i = 0; i < 4; ++i)
#pragma unroll
    for (int r = 0; r < 4; ++r) {
      int m = m0 + i * 16 + quad * 4 + r;
      float skv = skp[m];
      size_t mrow = (size_t)m * 768;
      const float* nqr = nq + (m & 15) * 768;
#pragma unroll
      for (int j = 0; j < 2; ++j) {
        float val = acc[i][j][r] + skv * bvj[j];
        float v = og * val + g * nqr[narr[j]];
        V32[mrow + narr[j]] = v;
        V16[mrow + narr[j]] = f2bf(v);
      }
    }
}

// ---------------- small MFMA GEMM 64x128, dual-output, 3-deep counted-vmcnt pipeline ----------------
__global__ __launch_bounds__(256) void gemm16s(const u16* __restrict__ A,
                                               const u16* __restrict__ BT0,
                                               const float* __restrict__ bias0,
                                               u16* __restrict__ C0, int N0, int ntA,
                                               const u16* __restrict__ BT1,
                                               const float* __restrict__ bias1,
                                               u16* __restrict__ C1, int N1, int ntB,
                                               int K) {
  __shared__ u16 As[3 * 64 * 32];
  __shared__ u16 Bs[3 * 128 * 32];
  int nt = ntA + ntB;
  int swz = xcd_swz();
  int mi = swz / nt, ni = swz % nt;
  const u16* BT; const float* bias; u16* C; int N, n0;
  if (ni < ntA) { BT = BT0; bias = bias0; C = C0; N = N0; n0 = ni * 128; }
  else          { BT = BT1; bias = bias1; C = C1; N = N1; n0 = (ni - ntA) * 128; }
  int m0 = mi * 64;
  int t = threadIdx.x;
  int wave = t >> 6, lane = t & 63, l16 = lane & 15, quad = lane >> 4;
  int ra = wave * 16 + (lane >> 2);
  int rb1 = wave * 32 + (lane >> 2);
  int rb2 = rb1 + 16;
  int cslot = lane & 3;
  int cga = (cslot ^ ((ra >> 1) & 3)) * 8;
  int cgb1 = (cslot ^ ((rb1 >> 1) & 3)) * 8;
  int cgb2 = (cslot ^ ((rb2 >> 1) & 3)) * 8;

  const u16* Ap = A + (size_t)(m0 + ra) * K + cga;
  const u16* Bp1 = BT + (size_t)(n0 + rb1) * K + cgb1;
  const u16* Bp2 = BT + (size_t)(n0 + rb2) * K + cgb2;
  u16* AsW = &As[(wave * 16) * 32];
  u16* BsW1 = &Bs[(wave * 32) * 32];
  u16* BsW2 = &Bs[(wave * 32 + 16) * 32];

  f32x4 zero4 = {0.f, 0.f, 0.f, 0.f};
  f32x4 acc[4][2];
#pragma unroll
  for (int i = 0; i < 4; ++i) { acc[i][0] = zero4; acc[i][1] = zero4; }

  STAGE3(0, 0); STAGE3(32, 1); STAGE3(64, 2);

  int bi = 0;
  for (int k0 = 0; k0 < K; k0 += 32) {
    int rem = (K - 32 - k0) >> 5;
    if (rem >= 2)      asm volatile("s_waitcnt vmcnt(6)" ::: "memory");
    else if (rem == 1) asm volatile("s_waitcnt vmcnt(3)" ::: "memory");
    else               asm volatile("s_waitcnt vmcnt(0)" ::: "memory");
    asm volatile("s_barrier" ::: "memory");
    const u16* Ab = &As[bi * 2048];
    const u16* Bb = &Bs[bi * 4096];
    short8 fa[4], fb[2];
#pragma unroll
    for (int i = 0; i < 4; ++i) {
      int R = i * 16 + l16;
      fa[i] = *(const short8*)&Ab[R * 32 + (quad ^ ((R >> 1) & 3)) * 8];
    }
#pragma unroll
    for (int j = 0; j < 2; ++j) {
      int R = wave * 32 + j * 16 + l16;
      fb[j] = *(const short8*)&Bb[R * 32 + (quad ^ ((R >> 1) & 3)) * 8];
    }
#pragma unroll
    for (int i = 0; i < 4; ++i)
#pragma unroll
      for (int j = 0; j < 2; ++j)
        acc[i][j] = __builtin_amdgcn_mfma_f32_16x16x32_bf16(fa[i], fb[j], acc[i][j], 0, 0, 0);
    asm volatile("s_barrier" ::: "memory");
    if (k0 + 96 < K) STAGE3(k0 + 96, bi);
    bi = bi + 1; if (bi == 3) bi = 0;
  }

  int narr[2]; float bvj[2];
#pragma unroll
  for (int j = 0; j < 2; ++j) {
    narr[j] = n0 + wave * 32 + j * 16 + l16;
    bvj[j] = bias ? bias[narr[j]] : 0.f;
  }
#pragma unroll
  for (int i = 0; i < 4; ++i)
#pragma unroll
    for (int r = 0; r < 4; ++r) {
      size_t mrow = (size_t)(m0 + i * 16 + quad * 4 + r) * N;
#pragma unroll
      for (int j = 0; j < 2; ++j)
        C[mrow + narr[j]] = f2bf(acc[i][j][r] + bvj[j]);
    }
}

// ---------------- edge logits (+softmax); grid (256 batches, 2 i-halves) ----------------
__global__ __launch_bounds__(256) void edge_kernel(const u16* __restrict__ HIJ,
                                                   const float* __restrict__ be1,
                                                   const float* __restrict__ We2,
                                                   const float* __restrict__ be2v,
                                                   float* __restrict__ Aout,
                                                   float* __restrict__ Eout) {
  __shared__ float hiS[8 * 516];
  __shared__ float hjS[16 * 516];
  __shared__ float be1s[512];
  __shared__ float w2s[512];
  int b = blockIdx.x, ih = blockIdx.y, t = threadIdx.x;
  be1s[t] = be1[t]; be1s[t + 256] = be1[t + 256];
  w2s[t] = We2[t];  w2s[t + 256] = We2[t + 256];

#pragma unroll
  for (int r = 0; r < 6; ++r) {
    int idx = t + 256 * r;  // 0..1535 short8 chunks
    const u16* src;
    float* dst;
    if (idx < 512) {
      int row = idx >> 6, c8 = idx & 63;
      src = &HIJ[(size_t)(b * 16 + ih * 8 + row) * 1024 + c8 * 8];
      dst = &hiS[row * 516 + c8 * 8];
    } else {
      int k = idx - 512;
      int row = k >> 6, c8 = k & 63;
      src = &HIJ[(size_t)(b * 16 + row) * 1024 + 512 + c8 * 8];
      dst = &hjS[row * 516 + c8 * 8];
    }
    short8 hv = *(const short8*)src;
    f32x4 l0, l1;
#pragma unroll
    for (int ee = 0; ee < 4; ++ee) { l0[ee] = bf2f((u16)hv[ee]); l1[ee] = bf2f((u16)hv[ee + 4]); }
    *(f32x4*)dst = l0;
    *(f32x4*)(dst + 4) = l1;
  }
  __syncthreads();

  int i_loc = t >> 5, j = (t >> 1) & 15, hh = t & 1;
  const float* hi = &hiS[i_loc * 516 + hh * 256];
  const float* hj = &hjS[j * 516 + hh * 256];
  const float* b1 = &be1s[hh * 256];
  const float* w2 = &w2s[hh * 256];
  float e = 0.f;
#pragma unroll 2
  for (int h4 = 0; h4 < 64; ++h4) {
    f32x4 hv = *(const f32x4*)&hi[h4 * 4];
    f32x4 jv = *(const f32x4*)&hj[h4 * 4];
    f32x4 bv = *(const f32x4*)&b1[h4 * 4];
    f32x4 wv = *(const f32x4*)&w2[h4 * 4];
#pragma unroll
    for (int ee = 0; ee < 4; ++ee)
      e += fmaxf(hv[ee] + jv[ee] + bv[ee], 0.f) * wv[ee];
  }
  e += __shfl_xor(e, 1);  // combine the two h-halves
  e += be2v[0];

  int pair = (ih * 8 + i_loc) * 16 + j;
  if (Aout) {
    float mx = e;
#pragma unroll
    for (int off = 2; off < 32; off <<= 1) mx = fmaxf(mx, __shfl_xor(mx, off));
    float ex = __expf(e - mx);
    float sm = ex;
#pragma unroll
    for (int off = 2; off < 32; off <<= 1) sm += __shfl_xor(sm, off);
    if (hh == 0) Aout[(size_t)b * 256 + pair] = ex / sm;
  }
  if (Eout && hh == 0) Eout[(size_t)b * 256 + pair] = e;
}

// ---------------- GNN combine: V += relu(A @ G); grid (256 batches, 3 d-chunks) ----------------
// Final layer (Vout != null): V32 store skipped (dead afterward).
__global__ __launch_bounds__(256) void combine_kernel(const float* __restrict__ Aws,
                                                      const u16* __restrict__ G,
                                                      float* __restrict__ V32,
                                                      u16* __restrict__ V16,
                                                      float* __restrict__ Vout) {
  __shared__ float Gs[16 * 260];
  __shared__ float As[256];
  int b = blockIdx.x, yc = blockIdx.y, t = threadIdx.x;
#pragma unroll
  for (int r = 0; r < 2; ++r) {
    int idx = t + 256 * r;          // 512 short8 chunks (16 rows x 32)
    int row = idx >> 5, c8 = idx & 31;
    short8 gv8 = *(const short8*)&G[(size_t)(b * 16 + row) * 768 + yc * 256 + c8 * 8];
    f32x4 l0, l1;
#pragma unroll
    for (int ee = 0; ee < 4; ++ee) { l0[ee] = bf2f((u16)gv8[ee]); l1[ee] = bf2f((u16)gv8[ee + 4]); }
    *(f32x4*)&Gs[row * 260 + c8 * 8] = l0;
    *(f32x4*)&Gs[row * 260 + c8 * 8 + 4] = l1;
  }
  As[t] = Aws[(size_t)b * 256 + t];
  __syncthreads();
  int d = yc * 256 + t;
  float gv[16];
#pragma unroll
  for (int j = 0; j < 16; ++j) gv[j] = Gs[j * 260 + t];
#pragma unroll
  for (int i = 0; i < 16; ++i) {
    float msg = 0.f;
#pragma unroll
    for (int j = 0; j < 16; ++j) msg += As[i * 16 + j] * gv[j];
    size_t idx = (size_t)b * 12288 + (size_t)i * 768 + d;
    float v = V32[idx] + fmaxf(msg, 0.f);
    if (Vout) { Vout[idx] = v; }   // final layer: V32 is dead, skip its store
    else      { V32[idx] = v; }
    V16[idx] = f2bf(v);
  }
}

extern "C" void kernel_launch(void* const* d_in, const int* in_sizes, int n_in,
                              void* d_out, int out_size, void* d_ws, size_t ws_size,
                              hipStream_t stream) {
  const float* w    = (const float*)d_in[0];   // [256,77,768]
  const int*   mask = (const int*)d_in[1];     // [256,77]
  const float* nq   = (const float*)d_in[2];   // [1,16,768]
  const float* Wq   = (const float*)d_in[3];
  const float* bq   = (const float*)d_in[4];
  const float* Wk   = (const float*)d_in[5];
  const float* bk   = (const float*)d_in[6];
  const float* Wv   = (const float*)d_in[7];
  const float* bv   = (const float*)d_in[8];
  const float* We1  = (const float*)d_in[9];   // [1536,512]
  const float* be1  = (const float*)d_in[10];
  const float* We2  = (const float*)d_in[11];  // [512,1]
  const float* be2  = (const float*)d_in[12];
  const float* gate = (const float*)d_in[13];
  const float* Wg   = (const float*)d_in[14];  // [2,768,768]
  const float* bg   = (const float*)d_in[15];  // [2,768]

  // workspace
  float* ws    = (float*)d_ws;
  float* V32   = ws;                    // 3,145,728 f
  float* Aws   = V32 + 3145728;         // 65,536 f
  float* Qpart = Aws + 65536;           // 98,304 f
  float* Qf    = Qpart + 98304;         // 12,288 f
  float* qb    = Qf + 12288;            // 16 f
  float* sk    = qb + 16;               // 4,096 f
  u16* PT16    = (u16*)(sk + 4096);     // 12,288 u16
  u16* WvT     = PT16 + 12288;          // 589,824
  u16* We1T    = WvT + 589824;          // 786,432
  u16* WgT     = We1T + 786432;         // 1,179,648
  u16* V16     = WgT + 1179648;         // 3,145,728
  u16* U16     = V16 + 3145728;         // 3,145,728
  u16* HIJ     = U16 + 3145728;         // 4,194,304
  u16* Gws     = HIJ + 4194304;         // 3,145,728

  float* out  = (float*)d_out;
  float* Sout = out;                       // [256,77,16]
  float* Vout = out + 315392;              // [256,16,768]
  float* Eout = out + 315392 + 3145728;    // [256,16,16]

  dim3 blk(256);

  // prep: weights -> bf16 [n][k]; Q (f32, split-K); PT/qb
  tcast_all<<<dim3(24, 24, 5), blk, 0, stream>>>(Wv, We1, Wg, WvT, We1T, WgT);
  q_part<<<dim3(48, 8), blk, 0, stream>>>(nq, Wq, Qpart);
  q_reduce<<<48, blk, 0, stream>>>(Qpart, bq, Qf);
  pt_kernel<<<49, blk, 0, stream>>>(Qf, Wk, bk, PT16, qb);

  // scores directly from f32 w (cast in-register); softmax -> Sout
  score2<<<308, blk, 0, stream>>>(w, PT16, qb, mask, Sout);

  // U = S^T @ w (per batch, f32) + colsums; V = U @ WvT + sk*bv, gate blend
  u_kernel<<<dim3(256, 3), blk, 0, stream>>>(Sout, w, U16, sk);
  vgemm<<<384, blk, 0, stream>>>(U16, WvT, sk, bv, nq, gate, V32, V16);

  // fused: pre-GNN edge gemm (HIJ, 8 n-tiles) + GNN layer-0 gemm (Gws, 6 n-tiles)
  gemm16s<<<896, blk, 0, stream>>>(V16, We1T, nullptr, HIJ, 1024, 8,
                                   WgT, bg, Gws, 768, 6, 768);
  // layer-0 edge (A) + combine
  edge_kernel<<<dim3(256, 2), blk, 0, stream>>>(HIJ, be1, We2, be2, Aws, (float*)nullptr);
  combine_kernel<<<dim3(256, 3), blk, 0, stream>>>(Aws, Gws, V32, V16, (float*)nullptr);

  // GNN layer 1
  gemm16s<<<384, blk, 0, stream>>>(V16, WgT + 589824, bg + 768, Gws, 768, 6,
                                   WgT + 589824, bg + 768, Gws, 768, 0, 768);
  combine_kernel<<<dim3(256, 3), blk, 0, stream>>>(Aws, Gws, V32, V16, Vout);

  // post-GNN edge logits -> E
  gemm16s<<<512, blk, 0, stream>>>(V16, We1T, nullptr, HIJ, 1024, 8,
                                   We1T, nullptr, HIJ, 1024, 0, 768);
  edge_kernel<<<dim3(256, 2), blk, 0, stream>>>(HIJ, be1, We2, be2, (float*)nullptr, Eout);
}

// Round 10
// 297.881 us; speedup vs baseline: 1.0615x; 1.0247x over previous
//
#include <hip/hip_runtime.h>

typedef unsigned short u16;
typedef __attribute__((ext_vector_type(8))) short short8;
typedef __attribute__((ext_vector_type(4))) float f32x4;

#define DEV static __device__ __forceinline__

DEV float bf2f(u16 u) { return __uint_as_float(((unsigned)u) << 16); }
DEV u16 f2bf(float f) {
  unsigned u = __float_as_uint(f);
  return (u16)((u + 0x7fffu + ((u >> 16) & 1u)) >> 16);
}

// async global->LDS, 16B per lane; LDS dest = wave-uniform base + lane*16
DEV void cp16(void* lds, const void* g) {
  __builtin_amdgcn_global_load_lds(
      (const __attribute__((address_space(1))) unsigned int*)g,
      (__attribute__((address_space(3))) unsigned int*)lds, 16, 0, 0);
}

// XCD-aware bijective swizzle; requires gridDim.x % 8 == 0
DEV int xcd_swz() {
  int bid = blockIdx.x;
  int cpx = gridDim.x >> 3;
  return (bid & 7) * cpx + (bid >> 3);
}

// dims: B=256, N=77, D=768, K=16, Dn=768, HID=512, L=2

// ---------------- weight transposes+casts in one launch (Wv, We1, Wg) ----------------
__global__ __launch_bounds__(256) void tcast_all(const float* __restrict__ Wv,
                                                 const float* __restrict__ We1,
                                                 const float* __restrict__ Wg,
                                                 u16* __restrict__ WvT,
                                                 u16* __restrict__ We1T,
                                                 u16* __restrict__ WgT) {
  __shared__ float tile[32][33];
  const float* src; u16* dst; int C;
  switch (blockIdx.z) {
    case 0: src = Wv;           dst = WvT;           C = 768; break;
    case 1: src = We1;          dst = We1T;          C = 512; break;
    case 2: src = We1 + 393216; dst = We1T + 393216; C = 512; break;
    case 3: src = Wg;           dst = WgT;           C = 768; break;
    default: src = Wg + 589824; dst = WgT + 589824;  C = 768; break;
  }
  int r0 = blockIdx.y * 32, c0 = blockIdx.x * 32;
  if (c0 >= C) return;
  int tr = threadIdx.x >> 5, tc = threadIdx.x & 31;
#pragma unroll
  for (int rr = 0; rr < 4; ++rr)
    tile[tr + rr * 8][tc] = src[(size_t)(r0 + tr + rr * 8) * C + c0 + tc];
  __syncthreads();
#pragma unroll
  for (int rr = 0; rr < 4; ++rr)
    dst[(size_t)(c0 + tr + rr * 8) * 768 + r0 + tc] = f2bf(tile[tc][tr + rr * 8]);
}

// ---------------- Q projection, split-K stage 1 ----------------
__global__ __launch_bounds__(256) void q_part(const float* __restrict__ nq,
                                              const float* __restrict__ Wq,
                                              float* __restrict__ Qpart) {
  int gid = blockIdx.x * 256 + threadIdx.x;  // 0..12287
  int s = blockIdx.y;
  int k = gid / 768, d = gid % 768;
  const float* nr = nq + k * 768 + s * 96;
  const float* wp = Wq + (size_t)(s * 96) * 768 + d;
  float s0 = 0.f, s1 = 0.f, s2 = 0.f, s3 = 0.f;
#pragma unroll
  for (int c = 0; c < 96; c += 4) {
    s0 += nr[c + 0] * wp[(size_t)(c + 0) * 768];
    s1 += nr[c + 1] * wp[(size_t)(c + 1) * 768];
    s2 += nr[c + 2] * wp[(size_t)(c + 2) * 768];
    s3 += nr[c + 3] * wp[(size_t)(c + 3) * 768];
  }
  Qpart[(size_t)s * 12288 + gid] = (s0 + s1) + (s2 + s3);
}

// ---------------- Q projection, stage 2: reduce + bias -> f32 Q ----------------
__global__ __launch_bounds__(256) void q_reduce(const float* __restrict__ Qpart,
                                                const float* __restrict__ bq,
                                                float* __restrict__ Qf) {
  int gid = blockIdx.x * 256 + threadIdx.x;  // 0..12287
  int d = gid % 768;
  float s = bq[d];
#pragma unroll
  for (int i = 0; i < 8; ++i) s += Qpart[(size_t)i * 12288 + gid];
  Qf[gid] = s;
}

// ---------------- PT[k,c] = sum_d Wk[c,d]*Q[k,d] (bf16); qb[k] = Q[k]·bk ----------------
__global__ __launch_bounds__(256) void pt_kernel(const float* __restrict__ Qf,
                                                 const float* __restrict__ Wk,
                                                 const float* __restrict__ bk,
                                                 u16* __restrict__ PT16,
                                                 float* __restrict__ qb) {
  int t = threadIdx.x;
  if (blockIdx.x == 48) {
    int k = t >> 4, j = t & 15;
    const float* q = Qf + k * 768 + j * 48;
    const float* bp = bk + j * 48;
    float s = 0.f;
#pragma unroll
    for (int d = 0; d < 48; d += 4) {
      f32x4 qv = *(const f32x4*)&q[d];
      f32x4 bv4 = *(const f32x4*)&bp[d];
      s += qv[0] * bv4[0] + qv[1] * bv4[1] + qv[2] * bv4[2] + qv[3] * bv4[3];
    }
#pragma unroll
    for (int off = 1; off < 16; off <<= 1) s += __shfl_xor(s, off);
    if (j == 0) qb[k] = s;
    return;
  }
  int gid = blockIdx.x * 256 + t;
  int c = gid >> 4, k = gid & 15;  // 16 threads share row c -> broadcast reads of Wk
  const float* wr = Wk + (size_t)c * 768;
  const float* q = Qf + k * 768;
  float s = 0.f;
  for (int d = 0; d < 768; d += 4) {
    f32x4 wv = *(const f32x4*)&wr[d];
    f32x4 qv = *(const f32x4*)&q[d];
    s += wv[0] * qv[0] + wv[1] * qv[1] + wv[2] * qv[2] + wv[3] * qv[3];
  }
  PT16[k * 768 + c] = f2bf(s);
}

// ---------------- scores via MFMA directly from f32 w (cast in-register) ----------------
__global__ __launch_bounds__(256) void score2(const float* __restrict__ w,
                                              const u16* __restrict__ PT16,
                                              const float* __restrict__ qb,
                                              const int* __restrict__ mask,
                                              float* __restrict__ Sout) {
  __shared__ u16 Ps[16 * 776];
  int t = threadIdx.x, wave = t >> 6, lane = t & 63, l16 = lane & 15, quad = lane >> 4;
  int m0 = blockIdx.x * 64;
#pragma unroll
  for (int r = 0; r < 6; ++r) {
    int idx = t + 256 * r;
    int row = idx / 96, c8 = idx % 96;
    *(short8*)&Ps[row * 776 + c8 * 8] = *(const short8*)&PT16[row * 768 + c8 * 8];
  }
  __syncthreads();
  int row = m0 + wave * 16 + l16;
  const float* ap = w + (size_t)row * 768 + quad * 8;
  f32x4 acc = {0.f, 0.f, 0.f, 0.f};
#pragma unroll
  for (int it = 0; it < 24; ++it) {
    f32x4 a0 = *(const f32x4*)(ap + it * 32);
    f32x4 a1 = *(const f32x4*)(ap + it * 32 + 4);
    short8 fa;
#pragma unroll
    for (int e = 0; e < 4; ++e) { fa[e] = (short)f2bf(a0[e]); fa[e + 4] = (short)f2bf(a1[e]); }
    short8 fb = *(const short8*)&Ps[l16 * 776 + it * 32 + quad * 8];
    acc = __builtin_amdgcn_mfma_f32_16x16x32_bf16(fa, fb, acc, 0, 0, 0);
  }
  float qv = qb[l16];
  const float scale = 0.1020620726159658f;  // (768/8)^-0.5
#pragma unroll
  for (int r = 0; r < 4; ++r) {
    int orow = m0 + wave * 16 + quad * 4 + r;
    float s = (acc[r] + qv) * scale;
    if (mask[orow] == 0) s = -3.402823466e38f;  // finfo(f32).min
    float mx = s;
#pragma unroll
    for (int off = 1; off < 16; off <<= 1) mx = fmaxf(mx, __shfl_xor(mx, off));
    float e = __expf(s - mx);
    float sm = e;
#pragma unroll
    for (int off = 1; off < 16; off <<= 1) sm += __shfl_xor(sm, off);
    Sout[(size_t)orow * 16 + l16] = e / sm;
  }
}

// ---------------- U[b] = S[b]^T @ w[b] (f32 direct); sk[b,k] = colsum S. grid (256,3) ----------------
__global__ __launch_bounds__(256) void u_kernel(const float* __restrict__ Sg,
                                                const float* __restrict__ w,
                                                u16* __restrict__ U16,
                                                float* __restrict__ sk) {
  __shared__ float Ss[1232];
  int b = blockIdx.x, t = threadIdx.x;
  int d = blockIdx.y * 256 + t;
#pragma unroll
  for (int r = 0; r < 5; ++r) {
    int idx = t + 256 * r;
    if (idx < 1232) Ss[idx] = Sg[(size_t)b * 1232 + idx];
  }
  __syncthreads();
  float a[16];
#pragma unroll
  for (int k = 0; k < 16; ++k) a[k] = 0.f;
  const float* wp = w + (size_t)b * 59136;  // 77*768
  for (int n = 0; n < 77; ++n) {
    float g = wp[(size_t)n * 768 + d];
    const float* sr = &Ss[n * 16];
#pragma unroll
    for (int k = 0; k < 16; ++k) a[k] += sr[k] * g;
  }
#pragma unroll
  for (int k = 0; k < 16; ++k)
    U16[(size_t)b * 12288 + (size_t)k * 768 + d] = f2bf(a[k]);
  if (blockIdx.y == 0 && t < 16) {
    float s = 0.f;
    for (int n = 0; n < 77; ++n) s += Ss[n * 16 + t];
    sk[b * 16 + t] = s;
  }
}

#define STAGE3(KOFF, BI)                          \
  do {                                            \
    cp16(AsW + (BI) * 2048, Ap + (KOFF));         \
    cp16(BsW1 + (BI) * 4096, Bp1 + (KOFF));       \
    cp16(BsW2 + (BI) * 4096, Bp2 + (KOFF));       \
  } while (0)

// ---------------- V = U @ WvT + sk*bv, gate blend. 3-deep counted-vmcnt pipeline ----------------
__global__ __launch_bounds__(256) void vgemm(const u16* __restrict__ A,
                                             const u16* __restrict__ BT,
                                             const float* __restrict__ skp,
                                             const float* __restrict__ bv,
                                             const float* __restrict__ nq,
                                             const float* __restrict__ gatep,
                                             float* __restrict__ V32,
                                             u16* __restrict__ V16) {
  __shared__ u16 As[3 * 64 * 32];
  __shared__ u16 Bs[3 * 128 * 32];
  int swz = xcd_swz();
  int mi = swz / 6, ni = swz % 6;
  int m0 = mi * 64, n0 = ni * 128;
  int t = threadIdx.x;
  int wave = t >> 6, lane = t & 63, l16 = lane & 15, quad = lane >> 4;
  int ra = wave * 16 + (lane >> 2);
  int rb1 = wave * 32 + (lane >> 2);
  int rb2 = rb1 + 16;
  int cslot = lane & 3;
  int cga = (cslot ^ ((ra >> 1) & 3)) * 8;
  int cgb1 = (cslot ^ ((rb1 >> 1) & 3)) * 8;
  int cgb2 = (cslot ^ ((rb2 >> 1) & 3)) * 8;

  const u16* Ap = A + (size_t)(m0 + ra) * 768 + cga;
  const u16* Bp1 = BT + (size_t)(n0 + rb1) * 768 + cgb1;
  const u16* Bp2 = BT + (size_t)(n0 + rb2) * 768 + cgb2;
  u16* AsW = &As[(wave * 16) * 32];
  u16* BsW1 = &Bs[(wave * 32) * 32];
  u16* BsW2 = &Bs[(wave * 32 + 16) * 32];

  f32x4 zero4 = {0.f, 0.f, 0.f, 0.f};
  f32x4 acc[4][2];
#pragma unroll
  for (int i = 0; i < 4; ++i) { acc[i][0] = zero4; acc[i][1] = zero4; }

  STAGE3(0, 0); STAGE3(32, 1); STAGE3(64, 2);

  int bi = 0;
  for (int k0 = 0; k0 < 768; k0 += 32) {
    int rem = (768 - 32 - k0) >> 5;
    if (rem >= 2)      asm volatile("s_waitcnt vmcnt(6)" ::: "memory");
    else if (rem == 1) asm volatile("s_waitcnt vmcnt(3)" ::: "memory");
    else               asm volatile("s_waitcnt vmcnt(0)" ::: "memory");
    asm volatile("s_barrier" ::: "memory");
    const u16* Ab = &As[bi * 2048];
    const u16* Bb = &Bs[bi * 4096];
    short8 fa[4], fb[2];
#pragma unroll
    for (int i = 0; i < 4; ++i) {
      int R = i * 16 + l16;
      fa[i] = *(const short8*)&Ab[R * 32 + (quad ^ ((R >> 1) & 3)) * 8];
    }
#pragma unroll
    for (int j = 0; j < 2; ++j) {
      int R = wave * 32 + j * 16 + l16;
      fb[j] = *(const short8*)&Bb[R * 32 + (quad ^ ((R >> 1) & 3)) * 8];
    }
#pragma unroll
    for (int i = 0; i < 4; ++i)
#pragma unroll
      for (int j = 0; j < 2; ++j)
        acc[i][j] = __builtin_amdgcn_mfma_f32_16x16x32_bf16(fa[i], fb[j], acc[i][j], 0, 0, 0);
    asm volatile("s_barrier" ::: "memory");
    if (k0 + 96 < 768) STAGE3(k0 + 96, bi);
    bi = bi + 1; if (bi == 3) bi = 0;
  }

  float gv = gatep[0];
  float g = 1.f / (1.f + __expf(-gv)), og = 1.f - g;
  int narr[2]; float bvj[2];
#pragma unroll
  for (int j = 0; j < 2; ++j) {
    narr[j] = n0 + wave * 32 + j * 16 + l16;
    bvj[j] = bv[narr[j]];
  }
#pragma unroll
  for (int i = 0; i < 4; ++i)
#pragma unroll
    for (int r = 0; r < 4; ++r) {
      int m = m0 + i * 16 + quad * 4 + r;
      float skv = skp[m];
      size_t mrow = (size_t)m * 768;
      const float* nqr = nq + (m & 15) * 768;
#pragma unroll
      for (int j = 0; j < 2; ++j) {
        float val = acc[i][j][r] + skv * bvj[j];
        float v = og * val + g * nqr[narr[j]];
        V32[mrow + narr[j]] = v;
        V16[mrow + narr[j]] = f2bf(v);
      }
    }
}

// ---------------- small MFMA GEMM 64x128, dual-output, 3-deep counted-vmcnt pipeline ----------------
__global__ __launch_bounds__(256) void gemm16s(const u16* __restrict__ A,
                                               const u16* __restrict__ BT0,
                                               const float* __restrict__ bias0,
                                               u16* __restrict__ C0, int N0, int ntA,
                                               const u16* __restrict__ BT1,
                                               const float* __restrict__ bias1,
                                               u16* __restrict__ C1, int N1, int ntB,
                                               int K) {
  __shared__ u16 As[3 * 64 * 32];
  __shared__ u16 Bs[3 * 128 * 32];
  int nt = ntA + ntB;
  int swz = xcd_swz();
  int mi = swz / nt, ni = swz % nt;
  const u16* BT; const float* bias; u16* C; int N, n0;
  if (ni < ntA) { BT = BT0; bias = bias0; C = C0; N = N0; n0 = ni * 128; }
  else          { BT = BT1; bias = bias1; C = C1; N = N1; n0 = (ni - ntA) * 128; }
  int m0 = mi * 64;
  int t = threadIdx.x;
  int wave = t >> 6, lane = t & 63, l16 = lane & 15, quad = lane >> 4;
  int ra = wave * 16 + (lane >> 2);
  int rb1 = wave * 32 + (lane >> 2);
  int rb2 = rb1 + 16;
  int cslot = lane & 3;
  int cga = (cslot ^ ((ra >> 1) & 3)) * 8;
  int cgb1 = (cslot ^ ((rb1 >> 1) & 3)) * 8;
  int cgb2 = (cslot ^ ((rb2 >> 1) & 3)) * 8;

  const u16* Ap = A + (size_t)(m0 + ra) * K + cga;
  const u16* Bp1 = BT + (size_t)(n0 + rb1) * K + cgb1;
  const u16* Bp2 = BT + (size_t)(n0 + rb2) * K + cgb2;
  u16* AsW = &As[(wave * 16) * 32];
  u16* BsW1 = &Bs[(wave * 32) * 32];
  u16* BsW2 = &Bs[(wave * 32 + 16) * 32];

  f32x4 zero4 = {0.f, 0.f, 0.f, 0.f};
  f32x4 acc[4][2];
#pragma unroll
  for (int i = 0; i < 4; ++i) { acc[i][0] = zero4; acc[i][1] = zero4; }

  STAGE3(0, 0); STAGE3(32, 1); STAGE3(64, 2);

  int bi = 0;
  for (int k0 = 0; k0 < K; k0 += 32) {
    int rem = (K - 32 - k0) >> 5;
    if (rem >= 2)      asm volatile("s_waitcnt vmcnt(6)" ::: "memory");
    else if (rem == 1) asm volatile("s_waitcnt vmcnt(3)" ::: "memory");
    else               asm volatile("s_waitcnt vmcnt(0)" ::: "memory");
    asm volatile("s_barrier" ::: "memory");
    const u16* Ab = &As[bi * 2048];
    const u16* Bb = &Bs[bi * 4096];
    short8 fa[4], fb[2];
#pragma unroll
    for (int i = 0; i < 4; ++i) {
      int R = i * 16 + l16;
      fa[i] = *(const short8*)&Ab[R * 32 + (quad ^ ((R >> 1) & 3)) * 8];
    }
#pragma unroll
    for (int j = 0; j < 2; ++j) {
      int R = wave * 32 + j * 16 + l16;
      fb[j] = *(const short8*)&Bb[R * 32 + (quad ^ ((R >> 1) & 3)) * 8];
    }
#pragma unroll
    for (int i = 0; i < 4; ++i)
#pragma unroll
      for (int j = 0; j < 2; ++j)
        acc[i][j] = __builtin_amdgcn_mfma_f32_16x16x32_bf16(fa[i], fb[j], acc[i][j], 0, 0, 0);
    asm volatile("s_barrier" ::: "memory");
    if (k0 + 96 < K) STAGE3(k0 + 96, bi);
    bi = bi + 1; if (bi == 3) bi = 0;
  }

  int narr[2]; float bvj[2];
#pragma unroll
  for (int j = 0; j < 2; ++j) {
    narr[j] = n0 + wave * 32 + j * 16 + l16;
    bvj[j] = bias ? bias[narr[j]] : 0.f;
  }
#pragma unroll
  for (int i = 0; i < 4; ++i)
#pragma unroll
    for (int r = 0; r < 4; ++r) {
      size_t mrow = (size_t)(m0 + i * 16 + quad * 4 + r) * N;
#pragma unroll
      for (int j = 0; j < 2; ++j)
        C[mrow + narr[j]] = f2bf(acc[i][j][r] + bvj[j]);
    }
}

// 128x128 staging, 2-deep double buffer
#define STG128(BI, KOFF)                                    \
  do {                                                      \
    cp16(&As[(BI) * 4096 + (wave * 32) * 32],      Ap1 + (KOFF)); \
    cp16(&As[(BI) * 4096 + (wave * 32 + 16) * 32], Ap2 + (KOFF)); \
    cp16(&Bs[(BI) * 4096 + (wave * 32) * 32],      Bp1 + (KOFF)); \
    cp16(&Bs[(BI) * 4096 + (wave * 32 + 16) * 32], Bp2 + (KOFF)); \
  } while (0)

// ---------------- big MFMA GEMM 128x128, dual-output, counted-vmcnt dbuf ----------------
// Use ONLY for launches with grid >= ~1.5 * 256 blocks (parallelism law).
__global__ __launch_bounds__(256) void gemm128(const u16* __restrict__ A,
                                               const u16* __restrict__ BT0,
                                               const float* __restrict__ bias0,
                                               u16* __restrict__ C0, int N0, int ntA,
                                               const u16* __restrict__ BT1,
                                               const float* __restrict__ bias1,
                                               u16* __restrict__ C1, int N1, int ntB,
                                               int K) {
  __shared__ u16 As[2 * 128 * 32];
  __shared__ u16 Bs[2 * 128 * 32];
  int nt = ntA + ntB;
  int swz = xcd_swz();
  int mi = swz / nt, ni = swz % nt;
  const u16* BT; const float* bias; u16* C; int N, n0;
  if (ni < ntA) { BT = BT0; bias = bias0; C = C0; N = N0; n0 = ni * 128; }
  else          { BT = BT1; bias = bias1; C = C1; N = N1; n0 = (ni - ntA) * 128; }
  int m0 = mi * 128;
  int t = threadIdx.x;
  int wave = t >> 6, lane = t & 63, l16 = lane & 15, quad = lane >> 4;
  int wrow = (wave >> 1) * 64, wcol = (wave & 1) * 64;
  int r1 = wave * 32 + (lane >> 2);
  int r2 = r1 + 16;
  int cslot = lane & 3;
  int cg1 = (cslot ^ ((r1 >> 1) & 3)) * 8;
  int cg2 = (cslot ^ ((r2 >> 1) & 3)) * 8;

  const u16* Ap1 = A + (size_t)(m0 + r1) * K + cg1;
  const u16* Ap2 = A + (size_t)(m0 + r2) * K + cg2;
  const u16* Bp1 = BT + (size_t)(n0 + r1) * K + cg1;
  const u16* Bp2 = BT + (size_t)(n0 + r2) * K + cg2;

  f32x4 zero4 = {0.f, 0.f, 0.f, 0.f};
  f32x4 acc[4][4];
#pragma unroll
  for (int i = 0; i < 4; ++i)
#pragma unroll
    for (int j = 0; j < 4; ++j) acc[i][j] = zero4;

  STG128(0, 0); STG128(1, 32);

  int cur = 0;
  for (int k0 = 0; k0 < K; k0 += 32) {
    if (k0 + 32 < K) asm volatile("s_waitcnt vmcnt(4)" ::: "memory");
    else             asm volatile("s_waitcnt vmcnt(0)" ::: "memory");
    asm volatile("s_barrier" ::: "memory");
    const u16* Ab = &As[cur * 4096];
    const u16* Bb = &Bs[cur * 4096];
    short8 fa[4], fb[4];
#pragma unroll
    for (int i = 0; i < 4; ++i) {
      int R = wrow + i * 16 + l16;
      fa[i] = *(const short8*)&Ab[R * 32 + (quad ^ ((R >> 1) & 3)) * 8];
    }
#pragma unroll
    for (int j = 0; j < 4; ++j) {
      int R = wcol + j * 16 + l16;
      fb[j] = *(const short8*)&Bb[R * 32 + (quad ^ ((R >> 1) & 3)) * 8];
    }
#pragma unroll
    for (int i = 0; i < 4; ++i)
#pragma unroll
      for (int j = 0; j < 4; ++j)
        acc[i][j] = __builtin_amdgcn_mfma_f32_16x16x32_bf16(fa[i], fb[j], acc[i][j], 0, 0, 0);
    asm volatile("s_barrier" ::: "memory");
    if (k0 + 64 < K) STG128(cur, k0 + 64);
    cur ^= 1;
  }

  int narr[4]; float bvj[4];
#pragma unroll
  for (int j = 0; j < 4; ++j) {
    narr[j] = n0 + wcol + j * 16 + l16;
    bvj[j] = bias ? bias[narr[j]] : 0.f;
  }
#pragma unroll
  for (int i = 0; i < 4; ++i)
#pragma unroll
    for (int r = 0; r < 4; ++r) {
      size_t mrow = (size_t)(m0 + wrow + i * 16 + quad * 4 + r) * N;
#pragma unroll
      for (int j = 0; j < 4; ++j)
        C[mrow + narr[j]] = f2bf(acc[i][j][r] + bvj[j]);
    }
}

// ---------------- edge logits (+softmax); grid (256 batches, 2 i-halves) ----------------
__global__ __launch_bounds__(256) void edge_kernel(const u16* __restrict__ HIJ,
                                                   const float* __restrict__ be1,
                                                   const float* __restrict__ We2,
                                                   const float* __restrict__ be2v,
                                                   float* __restrict__ Aout,
                                                   float* __restrict__ Eout) {
  __shared__ float hiS[8 * 516];
  __shared__ float hjS[16 * 516];
  __shared__ float be1s[512];
  __shared__ float w2s[512];
  int b = blockIdx.x, ih = blockIdx.y, t = threadIdx.x;
  be1s[t] = be1[t]; be1s[t + 256] = be1[t + 256];
  w2s[t] = We2[t];  w2s[t + 256] = We2[t + 256];

#pragma unroll
  for (int r = 0; r < 6; ++r) {
    int idx = t + 256 * r;  // 0..1535 short8 chunks
    const u16* src;
    float* dst;
    if (idx < 512) {
      int row = idx >> 6, c8 = idx & 63;
      src = &HIJ[(size_t)(b * 16 + ih * 8 + row) * 1024 + c8 * 8];
      dst = &hiS[row * 516 + c8 * 8];
    } else {
      int k = idx - 512;
      int row = k >> 6, c8 = k & 63;
      src = &HIJ[(size_t)(b * 16 + row) * 1024 + 512 + c8 * 8];
      dst = &hjS[row * 516 + c8 * 8];
    }
    short8 hv = *(const short8*)src;
    f32x4 l0, l1;
#pragma unroll
    for (int ee = 0; ee < 4; ++ee) { l0[ee] = bf2f((u16)hv[ee]); l1[ee] = bf2f((u16)hv[ee + 4]); }
    *(f32x4*)dst = l0;
    *(f32x4*)(dst + 4) = l1;
  }
  __syncthreads();

  int i_loc = t >> 5, j = (t >> 1) & 15, hh = t & 1;
  const float* hi = &hiS[i_loc * 516 + hh * 256];
  const float* hj = &hjS[j * 516 + hh * 256];
  const float* b1 = &be1s[hh * 256];
  const float* w2 = &w2s[hh * 256];
  float e = 0.f;
#pragma unroll 2
  for (int h4 = 0; h4 < 64; ++h4) {
    f32x4 hv = *(const f32x4*)&hi[h4 * 4];
    f32x4 jv = *(const f32x4*)&hj[h4 * 4];
    f32x4 bv = *(const f32x4*)&b1[h4 * 4];
    f32x4 wv = *(const f32x4*)&w2[h4 * 4];
#pragma unroll
    for (int ee = 0; ee < 4; ++ee)
      e += fmaxf(hv[ee] + jv[ee] + bv[ee], 0.f) * wv[ee];
  }
  e += __shfl_xor(e, 1);  // combine the two h-halves
  e += be2v[0];

  int pair = (ih * 8 + i_loc) * 16 + j;
  if (Aout) {
    float mx = e;
#pragma unroll
    for (int off = 2; off < 32; off <<= 1) mx = fmaxf(mx, __shfl_xor(mx, off));
    float ex = __expf(e - mx);
    float sm = ex;
#pragma unroll
    for (int off = 2; off < 32; off <<= 1) sm += __shfl_xor(sm, off);
    if (hh == 0) Aout[(size_t)b * 256 + pair] = ex / sm;
  }
  if (Eout && hh == 0) Eout[(size_t)b * 256 + pair] = e;
}

// ---------------- GNN combine: V += relu(A @ G); grid (256 batches, 3 d-chunks) ----------------
// Final layer (Vout != null): V32 store skipped (dead afterward).
__global__ __launch_bounds__(256) void combine_kernel(const float* __restrict__ Aws,
                                                      const u16* __restrict__ G,
                                                      float* __restrict__ V32,
                                                      u16* __restrict__ V16,
                                                      float* __restrict__ Vout) {
  __shared__ float Gs[16 * 260];
  __shared__ float As[256];
  int b = blockIdx.x, yc = blockIdx.y, t = threadIdx.x;
#pragma unroll
  for (int r = 0; r < 2; ++r) {
    int idx = t + 256 * r;          // 512 short8 chunks (16 rows x 32)
    int row = idx >> 5, c8 = idx & 31;
    short8 gv8 = *(const short8*)&G[(size_t)(b * 16 + row) * 768 + yc * 256 + c8 * 8];
    f32x4 l0, l1;
#pragma unroll
    for (int ee = 0; ee < 4; ++ee) { l0[ee] = bf2f((u16)gv8[ee]); l1[ee] = bf2f((u16)gv8[ee + 4]); }
    *(f32x4*)&Gs[row * 260 + c8 * 8] = l0;
    *(f32x4*)&Gs[row * 260 + c8 * 8 + 4] = l1;
  }
  As[t] = Aws[(size_t)b * 256 + t];
  __syncthreads();
  int d = yc * 256 + t;
  float gv[16];
#pragma unroll
  for (int j = 0; j < 16; ++j) gv[j] = Gs[j * 260 + t];
#pragma unroll
  for (int i = 0; i < 16; ++i) {
    float msg = 0.f;
#pragma unroll
    for (int j = 0; j < 16; ++j) msg += As[i * 16 + j] * gv[j];
    size_t idx = (size_t)b * 12288 + (size_t)i * 768 + d;
    float v = V32[idx] + fmaxf(msg, 0.f);
    if (Vout) { Vout[idx] = v; }   // final layer: V32 is dead, skip its store
    else      { V32[idx] = v; }
    V16[idx] = f2bf(v);
  }
}

extern "C" void kernel_launch(void* const* d_in, const int* in_sizes, int n_in,
                              void* d_out, int out_size, void* d_ws, size_t ws_size,
                              hipStream_t stream) {
  const float* w    = (const float*)d_in[0];   // [256,77,768]
  const int*   mask = (const int*)d_in[1];     // [256,77]
  const float* nq   = (const float*)d_in[2];   // [1,16,768]
  const float* Wq   = (const float*)d_in[3];
  const float* bq   = (const float*)d_in[4];
  const float* Wk   = (const float*)d_in[5];
  const float* bk   = (const float*)d_in[6];
  const float* Wv   = (const float*)d_in[7];
  const float* bv   = (const float*)d_in[8];
  const float* We1  = (const float*)d_in[9];   // [1536,512]
  const float* be1  = (const float*)d_in[10];
  const float* We2  = (const float*)d_in[11];  // [512,1]
  const float* be2  = (const float*)d_in[12];
  const float* gate = (const float*)d_in[13];
  const float* Wg   = (const float*)d_in[14];  // [2,768,768]
  const float* bg   = (const float*)d_in[15];  // [2,768]

  // workspace
  float* ws    = (float*)d_ws;
  float* V32   = ws;                    // 3,145,728 f
  float* Aws   = V32 + 3145728;         // 65,536 f
  float* Qpart = Aws + 65536;           // 98,304 f
  float* Qf    = Qpart + 98304;         // 12,288 f
  float* qb    = Qf + 12288;            // 16 f
  float* sk    = qb + 16;               // 4,096 f
  u16* PT16    = (u16*)(sk + 4096);     // 12,288 u16
  u16* WvT     = PT16 + 12288;          // 589,824
  u16* We1T    = WvT + 589824;          // 786,432
  u16* WgT     = We1T + 786432;         // 1,179,648
  u16* V16     = WgT + 1179648;         // 3,145,728
  u16* U16     = V16 + 3145728;         // 3,145,728
  u16* HIJ     = U16 + 3145728;         // 4,194,304
  u16* Gws     = HIJ + 4194304;         // 3,145,728

  float* out  = (float*)d_out;
  float* Sout = out;                       // [256,77,16]
  float* Vout = out + 315392;              // [256,16,768]
  float* Eout = out + 315392 + 3145728;    // [256,16,16]

  dim3 blk(256);

  // prep: weights -> bf16 [n][k]; Q (f32, split-K); PT/qb
  tcast_all<<<dim3(24, 24, 5), blk, 0, stream>>>(Wv, We1, Wg, WvT, We1T, WgT);
  q_part<<<dim3(48, 8), blk, 0, stream>>>(nq, Wq, Qpart);
  q_reduce<<<48, blk, 0, stream>>>(Qpart, bq, Qf);
  pt_kernel<<<49, blk, 0, stream>>>(Qf, Wk, bk, PT16, qb);

  // scores directly from f32 w (cast in-register); softmax -> Sout
  score2<<<308, blk, 0, stream>>>(w, PT16, qb, mask, Sout);

  // U = S^T @ w (per batch, f32) + colsums; V = U @ WvT + sk*bv, gate blend
  u_kernel<<<dim3(256, 3), blk, 0, stream>>>(Sout, w, U16, sk);
  vgemm<<<384, blk, 0, stream>>>(U16, WvT, sk, bv, nq, gate, V32, V16);

  // fused: pre-GNN edge gemm (HIJ, 8 n-tiles) + GNN layer-0 gemm (Gws, 6 n-tiles)
  // ISOLATED CHANGE: 128x128 tile here only (448 blocks = 1.75/CU, above threshold)
  gemm128<<<448, blk, 0, stream>>>(V16, We1T, nullptr, HIJ, 1024, 8,
                                   WgT, bg, Gws, 768, 6, 768);
  // layer-0 edge (A) + combine
  edge_kernel<<<dim3(256, 2), blk, 0, stream>>>(HIJ, be1, We2, be2, Aws, (float*)nullptr);
  combine_kernel<<<dim3(256, 3), blk, 0, stream>>>(Aws, Gws, V32, V16, (float*)nullptr);

  // GNN layer 1 (64x128 tile keeps grid at 384)
  gemm16s<<<384, blk, 0, stream>>>(V16, WgT + 589824, bg + 768, Gws, 768, 6,
                                   WgT + 589824, bg + 768, Gws, 768, 0, 768);
  combine_kernel<<<dim3(256, 3), blk, 0, stream>>>(Aws, Gws, V32, V16, Vout);

  // post-GNN edge logits -> E (64x128 tile keeps grid at 512)
  gemm16s<<<512, blk, 0, stream>>>(V16, We1T, nullptr, HIJ, 1024, 8,
                                   We1T, nullptr, HIJ, 1024, 0, 768);
  edge_kernel<<<dim3(256, 2), blk, 0, stream>>>(HIJ, be1, We2, be2, (float*)nullptr, Eout);
}